// Round 1
// baseline (385.650 us; speedup 1.0000x reference)
//
#include <hip/hip_runtime.h>
#include <hip/hip_bf16.h>

#define N_NODES 500000
#define N_ELEM  1000000
#define N_PTS   8388608

// One thread handles 4 consecutive points:
//  - int4 load of cell_id
//  - 3x float4 load of shape_functions (12 floats, 16B-aligned since 48*t)
//  - per point: gather 3-int connectivity row, 6 nodal floats, 2 dot products
//  - float4 store per output dim
__global__ __launch_bounds__(256) void interp2d_kernel(
    const float* __restrict__ nodal,   // (2, N_NODES)
    const float4* __restrict__ sf4,    // shape_functions viewed as float4[3*N_PTS/4]
    const int* __restrict__ conn,      // (N_ELEM, 3), 1-based node ids
    const int4* __restrict__ cell4,    // cell_id viewed as int4[N_PTS/4]
    float* __restrict__ out)           // (2, N_PTS)
{
    const int t = blockIdx.x * blockDim.x + threadIdx.x;
    if (t >= N_PTS / 4) return;

    const int4 cid = cell4[t];

    const float4 s0 = sf4[3 * t + 0];
    const float4 s1 = sf4[3 * t + 1];
    const float4 s2 = sf4[3 * t + 2];

    const float w[4][3] = {
        {s0.x, s0.y, s0.z},
        {s0.w, s1.x, s1.y},
        {s1.z, s1.w, s2.x},
        {s2.y, s2.z, s2.w},
    };
    const int cids[4] = {cid.x, cid.y, cid.z, cid.w};

    float u0[4], u1[4];
#pragma unroll
    for (int j = 0; j < 4; ++j) {
        const int* cr = conn + 3 * (long)cids[j];
        const int i0 = cr[0] - 1;
        const int i1 = cr[1] - 1;
        const int i2 = cr[2] - 1;
        u0[j] = w[j][0] * nodal[i0]
              + w[j][1] * nodal[i1]
              + w[j][2] * nodal[i2];
        u1[j] = w[j][0] * nodal[N_NODES + i0]
              + w[j][1] * nodal[N_NODES + i1]
              + w[j][2] * nodal[N_NODES + i2];
    }

    float4 o0 = make_float4(u0[0], u0[1], u0[2], u0[3]);
    float4 o1 = make_float4(u1[0], u1[1], u1[2], u1[3]);
    reinterpret_cast<float4*>(out)[t] = o0;
    reinterpret_cast<float4*>(out + N_PTS)[t] = o1;
}

extern "C" void kernel_launch(void* const* d_in, const int* in_sizes, int n_in,
                              void* d_out, int out_size, void* d_ws, size_t ws_size,
                              hipStream_t stream) {
    const float* nodal = (const float*)d_in[0];        // (2, N_NODES)
    const float* sf    = (const float*)d_in[1];        // (N_PTS, 3)
    const int*   conn  = (const int*)d_in[2];          // (N_ELEM, 3)
    const int*   cell  = (const int*)d_in[3];          // (N_PTS,)
    float* out = (float*)d_out;                        // (2, N_PTS)

    const int n_threads = N_PTS / 4;                   // 2097152
    const int block = 256;
    const int grid = (n_threads + block - 1) / block;  // 8192

    interp2d_kernel<<<grid, block, 0, stream>>>(
        nodal,
        reinterpret_cast<const float4*>(sf),
        conn,
        reinterpret_cast<const int4*>(cell),
        out);
}

// Round 3
// 174.102 us; speedup vs baseline: 2.2151x; 2.2151x over previous
//
#include <hip/hip_runtime.h>
#include <hip/hip_bf16.h>

#define N_NODES 500000
#define N_ELEM  1000000
#define N_PTS   8388608

typedef float f32x4 __attribute__((ext_vector_type(4)));
typedef int   i32x4 __attribute__((ext_vector_type(4)));
typedef unsigned int u32x4 __attribute__((ext_vector_type(4)));

// ---------------------------------------------------------------------------
// Pre-pass: per element, gather the 6 nodal floats (3 nodes x 2 dims), convert
// to bf16, and pack into one 16-byte aligned row of d_ws:
//   row = { v00|v01, v02|v10, v11|v12, 0 }  (lo|hi 16-bit halves per u32)
// where vDK = nodal[dim D][node K].
// ---------------------------------------------------------------------------
__global__ __launch_bounds__(256) void pack_kernel(
    const float* __restrict__ nodal,   // (2, N_NODES)
    const int* __restrict__ conn,      // (N_ELEM, 3), 1-based
    u32x4* __restrict__ packed)        // (N_ELEM) 16B rows
{
    const int e = blockIdx.x * blockDim.x + threadIdx.x;
    if (e >= N_ELEM) return;

    const int* cr = conn + 3l * e;
    const int i0 = cr[0] - 1;
    const int i1 = cr[1] - 1;
    const int i2 = cr[2] - 1;

    float v[6];
    v[0] = nodal[i0];
    v[1] = nodal[i1];
    v[2] = nodal[i2];
    v[3] = nodal[N_NODES + i0];
    v[4] = nodal[N_NODES + i1];
    v[5] = nodal[N_NODES + i2];

    unsigned int h[6];
#pragma unroll
    for (int k = 0; k < 6; ++k) {
        // round-to-nearest-even f32 -> bf16
        unsigned int bits = __float_as_uint(v[k]);
        h[k] = (bits + 0x7FFFu + ((bits >> 16) & 1u)) >> 16;
    }

    u32x4 row;
    row.x = h[0] | (h[1] << 16);
    row.y = h[2] | (h[3] << 16);
    row.z = h[4] | (h[5] << 16);
    row.w = 0;
    packed[e] = row;
}

__device__ __forceinline__ float bf_lo(unsigned int u) {
    return __uint_as_float(u << 16);
}
__device__ __forceinline__ float bf_hi(unsigned int u) {
    return __uint_as_float(u & 0xFFFF0000u);
}

// ---------------------------------------------------------------------------
// Main pass: 1 thread = 4 consecutive points. Streaming loads are nontemporal
// (keep L2 for the packed gather table). One 16B aligned gather per point.
// ---------------------------------------------------------------------------
__global__ __launch_bounds__(256) void interp2d_packed_kernel(
    const u32x4* __restrict__ packed,  // (N_ELEM) 16B rows in d_ws
    const f32x4* __restrict__ sf4,     // shape_functions as f32x4[3*N_PTS/4]
    const i32x4* __restrict__ cell4,   // cell_id as i32x4[N_PTS/4]
    float* __restrict__ out)           // (2, N_PTS)
{
    const int t = blockIdx.x * blockDim.x + threadIdx.x;
    if (t >= N_PTS / 4) return;

    const i32x4 cid = __builtin_nontemporal_load(&cell4[t]);
    const f32x4 s0 = __builtin_nontemporal_load(&sf4[3 * t + 0]);
    const f32x4 s1 = __builtin_nontemporal_load(&sf4[3 * t + 1]);
    const f32x4 s2 = __builtin_nontemporal_load(&sf4[3 * t + 2]);

    const float w[4][3] = {
        {s0.x, s0.y, s0.z},
        {s0.w, s1.x, s1.y},
        {s1.z, s1.w, s2.x},
        {s2.y, s2.z, s2.w},
    };
    const int cids[4] = {cid.x, cid.y, cid.z, cid.w};

    float u0[4], u1[4];
#pragma unroll
    for (int j = 0; j < 4; ++j) {
        const u32x4 row = packed[cids[j]];
        const float v00 = bf_lo(row.x), v01 = bf_hi(row.x);
        const float v02 = bf_lo(row.y), v10 = bf_hi(row.y);
        const float v11 = bf_lo(row.z), v12 = bf_hi(row.z);
        u0[j] = w[j][0] * v00 + w[j][1] * v01 + w[j][2] * v02;
        u1[j] = w[j][0] * v10 + w[j][1] * v11 + w[j][2] * v12;
    }

    f32x4 o0 = {u0[0], u0[1], u0[2], u0[3]};
    f32x4 o1 = {u1[0], u1[1], u1[2], u1[3]};
    __builtin_nontemporal_store(o0, &reinterpret_cast<f32x4*>(out)[t]);
    __builtin_nontemporal_store(o1, &reinterpret_cast<f32x4*>(out + N_PTS)[t]);
}

// ---------------------------------------------------------------------------
// Fallback (ws too small): direct double-indirection kernel (round-1 version).
// ---------------------------------------------------------------------------
__global__ __launch_bounds__(256) void interp2d_direct_kernel(
    const float* __restrict__ nodal,
    const f32x4* __restrict__ sf4,
    const int* __restrict__ conn,
    const i32x4* __restrict__ cell4,
    float* __restrict__ out)
{
    const int t = blockIdx.x * blockDim.x + threadIdx.x;
    if (t >= N_PTS / 4) return;

    const i32x4 cid = cell4[t];
    const f32x4 s0 = sf4[3 * t + 0];
    const f32x4 s1 = sf4[3 * t + 1];
    const f32x4 s2 = sf4[3 * t + 2];

    const float w[4][3] = {
        {s0.x, s0.y, s0.z},
        {s0.w, s1.x, s1.y},
        {s1.z, s1.w, s2.x},
        {s2.y, s2.z, s2.w},
    };
    const int cids[4] = {cid.x, cid.y, cid.z, cid.w};

    float u0[4], u1[4];
#pragma unroll
    for (int j = 0; j < 4; ++j) {
        const int* cr = conn + 3 * (long)cids[j];
        const int i0 = cr[0] - 1;
        const int i1 = cr[1] - 1;
        const int i2 = cr[2] - 1;
        u0[j] = w[j][0] * nodal[i0] + w[j][1] * nodal[i1] + w[j][2] * nodal[i2];
        u1[j] = w[j][0] * nodal[N_NODES + i0] + w[j][1] * nodal[N_NODES + i1]
              + w[j][2] * nodal[N_NODES + i2];
    }

    f32x4 o0 = {u0[0], u0[1], u0[2], u0[3]};
    f32x4 o1 = {u1[0], u1[1], u1[2], u1[3]};
    reinterpret_cast<f32x4*>(out)[t] = o0;
    reinterpret_cast<f32x4*>(out + N_PTS)[t] = o1;
}

extern "C" void kernel_launch(void* const* d_in, const int* in_sizes, int n_in,
                              void* d_out, int out_size, void* d_ws, size_t ws_size,
                              hipStream_t stream) {
    const float* nodal = (const float*)d_in[0];        // (2, N_NODES)
    const float* sf    = (const float*)d_in[1];        // (N_PTS, 3)
    const int*   conn  = (const int*)d_in[2];          // (N_ELEM, 3)
    const int*   cell  = (const int*)d_in[3];          // (N_PTS,)
    float* out = (float*)d_out;                        // (2, N_PTS)

    const int n_threads = N_PTS / 4;                   // 2097152
    const int block = 256;
    const int grid = (n_threads + block - 1) / block;  // 8192

    const size_t packed_bytes = (size_t)N_ELEM * 16;   // 16 MB

    if (ws_size >= packed_bytes) {
        u32x4* packed = (u32x4*)d_ws;
        pack_kernel<<<(N_ELEM + block - 1) / block, block, 0, stream>>>(
            nodal, conn, packed);
        interp2d_packed_kernel<<<grid, block, 0, stream>>>(
            packed,
            reinterpret_cast<const f32x4*>(sf),
            reinterpret_cast<const i32x4*>(cell),
            out);
    } else {
        interp2d_direct_kernel<<<grid, block, 0, stream>>>(
            nodal,
            reinterpret_cast<const f32x4*>(sf),
            conn,
            reinterpret_cast<const i32x4*>(cell),
            out);
    }
}

// Round 4
// 169.117 us; speedup vs baseline: 2.2804x; 1.0295x over previous
//
#include <hip/hip_runtime.h>
#include <hip/hip_bf16.h>

#define N_NODES 500000
#define N_ELEM  1000000
#define N_PTS   8388608

typedef float f32x4 __attribute__((ext_vector_type(4)));
typedef int   i32x4 __attribute__((ext_vector_type(4)));
typedef unsigned int u32x2 __attribute__((ext_vector_type(2)));
typedef unsigned int u32x8 __attribute__((ext_vector_type(8)));

// ---------------------------------------------------------------------------
// Block-scaled row format (8 bytes per element):
//   six signed 10-bit mantissas q0..q5 + shared 4-bit exponent eb = e+8
//   v_k = q_k * 2^(e-9),  e chosen so max|v| / 2^e in [0.5, 1)
//   lo = q0 | q1<<10 | q2<<20 | (eb&3)<<30
//   hi = q3 | q4<<10 | q5<<20 | (eb>>2)<<30
//   order: q0..q2 = dim0 nodes 0..2, q3..q5 = dim1 nodes 0..2
// Absolute error per value <= max|v| * 2^-9 (same bound as bf16).
// ---------------------------------------------------------------------------
__device__ __forceinline__ u32x2 encode6(const float v[6]) {
    float m = fabsf(v[0]);
#pragma unroll
    for (int k = 1; k < 6; ++k) m = fmaxf(m, fabsf(v[k]));
    unsigned mb = __float_as_uint(m);
    int e = (int)(mb >> 23) - 127 + 1;       // m / 2^e in [0.5, 1)
    e = min(7, max(-8, e));
    // inv = 2^(9-e);  q = round(v * inv), clamped to [-512, 511]
    const float inv = __uint_as_float((unsigned)(9 - e + 127) << 23);
    int q[6];
#pragma unroll
    for (int k = 0; k < 6; ++k) {
        int qi = __float2int_rn(v[k] * inv);
        q[k] = min(511, max(-512, qi));
    }
    const unsigned eb = (unsigned)(e + 8);
    u32x2 row;
    row.x = (q[0] & 1023u) | ((q[1] & 1023u) << 10) | ((q[2] & 1023u) << 20)
          | ((eb & 3u) << 30);
    row.y = (q[3] & 1023u) | ((q[4] & 1023u) << 10) | ((q[5] & 1023u) << 20)
          | ((eb >> 2) << 30);
    return row;
}

// ---------------------------------------------------------------------------
// Pre-pass: 1 thread = 4 elements. Streaming conn loads (3x int4 = 48B),
// 24 gathers from the 4MB nodal table (L2-resident), 32B packed store.
// ---------------------------------------------------------------------------
__global__ __launch_bounds__(256) void pack_kernel(
    const float* __restrict__ nodal,   // (2, N_NODES)
    const i32x4* __restrict__ conn4,   // (N_ELEM, 3) viewed as int4
    u32x8* __restrict__ packed8)       // N_ELEM/4 rows of 32B
{
    const int t = blockIdx.x * blockDim.x + threadIdx.x;
    if (t >= N_ELEM / 4) return;

    const i32x4 c0 = __builtin_nontemporal_load(&conn4[3 * t + 0]);
    const i32x4 c1 = __builtin_nontemporal_load(&conn4[3 * t + 1]);
    const i32x4 c2 = __builtin_nontemporal_load(&conn4[3 * t + 2]);
    const int idx[12] = {c0.x - 1, c0.y - 1, c0.z - 1, c0.w - 1,
                         c1.x - 1, c1.y - 1, c1.z - 1, c1.w - 1,
                         c2.x - 1, c2.y - 1, c2.z - 1, c2.w - 1};

    u32x8 outrow;
#pragma unroll
    for (int el = 0; el < 4; ++el) {
        const int n0 = idx[3 * el + 0];
        const int n1 = idx[3 * el + 1];
        const int n2 = idx[3 * el + 2];
        float v[6];
        v[0] = nodal[n0];
        v[1] = nodal[n1];
        v[2] = nodal[n2];
        v[3] = nodal[N_NODES + n0];
        v[4] = nodal[N_NODES + n1];
        v[5] = nodal[N_NODES + n2];
        const u32x2 r = encode6(v);
        outrow[2 * el + 0] = r.x;
        outrow[2 * el + 1] = r.y;
    }
    __builtin_nontemporal_store(outrow, &packed8[t]);
}

// ---------------------------------------------------------------------------
// Main pass: 1 thread = 8 consecutive points.
//   streaming: 2x int4 cell ids, 6x float4 shape funcs (nontemporal)
//   gather:    8 independent 8B loads from the 8MB packed table
//   decode:    6x bfe + 6x cvt + 3 fma + mul per dim
// ---------------------------------------------------------------------------
__global__ __launch_bounds__(256) void interp2d_packed_kernel(
    const u32x2* __restrict__ packed,  // (N_ELEM) 8B rows in d_ws
    const f32x4* __restrict__ sf4,     // shape_functions as f32x4
    const i32x4* __restrict__ cell4,   // cell_id as i32x4
    float* __restrict__ out)           // (2, N_PTS)
{
    const int t = blockIdx.x * blockDim.x + threadIdx.x;
    if (t >= N_PTS / 8) return;

    const i32x4 ca = __builtin_nontemporal_load(&cell4[2 * t + 0]);
    const i32x4 cb = __builtin_nontemporal_load(&cell4[2 * t + 1]);
    const int cids[8] = {ca.x, ca.y, ca.z, ca.w, cb.x, cb.y, cb.z, cb.w};

    // issue all 8 gathers first (independent, maximize MLP)
    u32x2 row[8];
#pragma unroll
    for (int j = 0; j < 8; ++j) row[j] = packed[cids[j]];

    f32x4 s[6];
#pragma unroll
    for (int k = 0; k < 6; ++k)
        s[k] = __builtin_nontemporal_load(&sf4[6 * t + k]);

    float w[24];
#pragma unroll
    for (int k = 0; k < 6; ++k) {
        w[4 * k + 0] = s[k].x;
        w[4 * k + 1] = s[k].y;
        w[4 * k + 2] = s[k].z;
        w[4 * k + 3] = s[k].w;
    }

    float u0[8], u1[8];
#pragma unroll
    for (int j = 0; j < 8; ++j) {
        const unsigned lo = row[j].x;
        const unsigned hi = row[j].y;
        const unsigned eb = ((lo >> 30) & 3u) | (((hi >> 30) & 3u) << 2);
        const float scale = __uint_as_float((eb + 110u) << 23);
        const float f0 = (float)(((int)(lo << 22)) >> 22);
        const float f1 = (float)(((int)(lo << 12)) >> 22);
        const float f2 = (float)(((int)(lo <<  2)) >> 22);
        const float f3 = (float)(((int)(hi << 22)) >> 22);
        const float f4 = (float)(((int)(hi << 12)) >> 22);
        const float f5 = (float)(((int)(hi <<  2)) >> 22);
        const float w0 = w[3 * j + 0];
        const float w1 = w[3 * j + 1];
        const float w2 = w[3 * j + 2];
        u0[j] = (w0 * f0 + w1 * f1 + w2 * f2) * scale;
        u1[j] = (w0 * f3 + w1 * f4 + w2 * f5) * scale;
    }

    f32x4 o0a = {u0[0], u0[1], u0[2], u0[3]};
    f32x4 o0b = {u0[4], u0[5], u0[6], u0[7]};
    f32x4 o1a = {u1[0], u1[1], u1[2], u1[3]};
    f32x4 o1b = {u1[4], u1[5], u1[6], u1[7]};
    f32x4* out0 = reinterpret_cast<f32x4*>(out);
    f32x4* out1 = reinterpret_cast<f32x4*>(out + N_PTS);
    __builtin_nontemporal_store(o0a, &out0[2 * t + 0]);
    __builtin_nontemporal_store(o0b, &out0[2 * t + 1]);
    __builtin_nontemporal_store(o1a, &out1[2 * t + 0]);
    __builtin_nontemporal_store(o1b, &out1[2 * t + 1]);
}

// ---------------------------------------------------------------------------
// Fallback (ws too small): direct double-indirection kernel.
// ---------------------------------------------------------------------------
__global__ __launch_bounds__(256) void interp2d_direct_kernel(
    const float* __restrict__ nodal,
    const f32x4* __restrict__ sf4,
    const int* __restrict__ conn,
    const i32x4* __restrict__ cell4,
    float* __restrict__ out)
{
    const int t = blockIdx.x * blockDim.x + threadIdx.x;
    if (t >= N_PTS / 4) return;

    const i32x4 cid = cell4[t];
    const f32x4 s0 = sf4[3 * t + 0];
    const f32x4 s1 = sf4[3 * t + 1];
    const f32x4 s2 = sf4[3 * t + 2];

    const float w[4][3] = {
        {s0.x, s0.y, s0.z},
        {s0.w, s1.x, s1.y},
        {s1.z, s1.w, s2.x},
        {s2.y, s2.z, s2.w},
    };
    const int cids[4] = {cid.x, cid.y, cid.z, cid.w};

    float u0[4], u1[4];
#pragma unroll
    for (int j = 0; j < 4; ++j) {
        const int* cr = conn + 3 * (long)cids[j];
        const int i0 = cr[0] - 1;
        const int i1 = cr[1] - 1;
        const int i2 = cr[2] - 1;
        u0[j] = w[j][0] * nodal[i0] + w[j][1] * nodal[i1] + w[j][2] * nodal[i2];
        u1[j] = w[j][0] * nodal[N_NODES + i0] + w[j][1] * nodal[N_NODES + i1]
              + w[j][2] * nodal[N_NODES + i2];
    }

    f32x4 o0 = {u0[0], u0[1], u0[2], u0[3]};
    f32x4 o1 = {u1[0], u1[1], u1[2], u1[3]};
    reinterpret_cast<f32x4*>(out)[t] = o0;
    reinterpret_cast<f32x4*>(out + N_PTS)[t] = o1;
}

extern "C" void kernel_launch(void* const* d_in, const int* in_sizes, int n_in,
                              void* d_out, int out_size, void* d_ws, size_t ws_size,
                              hipStream_t stream) {
    const float* nodal = (const float*)d_in[0];        // (2, N_NODES)
    const float* sf    = (const float*)d_in[1];        // (N_PTS, 3)
    const int*   conn  = (const int*)d_in[2];          // (N_ELEM, 3)
    const int*   cell  = (const int*)d_in[3];          // (N_PTS,)
    float* out = (float*)d_out;                        // (2, N_PTS)

    const int block = 256;
    const size_t packed_bytes = (size_t)N_ELEM * 8;    // 8 MB

    if (ws_size >= packed_bytes) {
        const int e4 = N_ELEM / 4;                     // 250000
        pack_kernel<<<(e4 + block - 1) / block, block, 0, stream>>>(
            nodal,
            reinterpret_cast<const i32x4*>(conn),
            (u32x8*)d_ws);

        const int p8 = N_PTS / 8;                      // 1048576
        interp2d_packed_kernel<<<p8 / block, block, 0, stream>>>(
            (const u32x2*)d_ws,
            reinterpret_cast<const f32x4*>(sf),
            reinterpret_cast<const i32x4*>(cell),
            out);
    } else {
        const int n_threads = N_PTS / 4;
        interp2d_direct_kernel<<<(n_threads + block - 1) / block, block, 0, stream>>>(
            nodal,
            reinterpret_cast<const f32x4*>(sf),
            conn,
            reinterpret_cast<const i32x4*>(cell),
            out);
    }
}